// Round 6
// baseline (472.555 us; speedup 1.0000x reference)
//
#include <hip/hip_runtime.h>

#define NB    8
#define CDIM  768
#define NTOK  1024
#define NHEAD 12
#define DHEAD 64
#define C3    2304

typedef unsigned short u16;
typedef short  s8v __attribute__((ext_vector_type(8)));
typedef float  f4v __attribute__((ext_vector_type(4)));

#define MFMA16(a, b, c) __builtin_amdgcn_mfma_f32_16x16x32_bf16((a), (b), (c), 0, 0, 0)
#define LOG2E 1.4426950408889634f

static __device__ __forceinline__ u16 f2bf(float f) {
    unsigned u = __float_as_uint(f);
    u += 0x7fffu + ((u >> 16) & 1u);
    return (u16)(u >> 16);
}
static __device__ __forceinline__ float bf2f(u16 b) {
    return __uint_as_float(((unsigned)b) << 16);
}
static __device__ __forceinline__ unsigned packsplit(float x) {
    u16 h = f2bf(x);
    u16 l = f2bf(x - bf2f(h));
    return (unsigned)h | ((unsigned)l << 16);
}
static __device__ __forceinline__ void unpack8(uint4 a, uint4 b, s8v& h, s8v& l) {
    h = (s8v){(short)a.x, (short)a.y, (short)a.z, (short)a.w,
              (short)b.x, (short)b.y, (short)b.z, (short)b.w};
    l = (s8v){(short)(a.x >> 16), (short)(a.y >> 16), (short)(a.z >> 16), (short)(a.w >> 16),
              (short)(b.x >> 16), (short)(b.y >> 16), (short)(b.z >> 16), (short)(b.w >> 16)};
}
// SW32: swizzle for K-innermost bf16 arrays consumed as [row][32] BK=32 LDS tiles
static __device__ __forceinline__ int sw32i(int row, int k) {
    int g = (k >> 3) & 3;
    int gs = g ^ ((row >> 1) & 3);
    return (k & ~31) + (gs << 3) + (k & 7);
}
// async global->LDS 16B/lane: dst is WAVE-UNIFORM base (HW adds lane*16)
static __device__ __forceinline__ void gload16(const u16* gsrc, u16* ldst) {
    __builtin_amdgcn_global_load_lds(
        (const __attribute__((address_space(1))) void*)gsrc,
        (__attribute__((address_space(3))) void*)ldst, 16, 0, 0);
}

// ---------------------------------------------------------------------------
// 0a: x[b][c][p] fp32 -> xh/xl [b*p][c] bf16 split, SW32-swizzled by row m.
// ---------------------------------------------------------------------------
__launch_bounds__(256)
__global__ void split_x(const float* __restrict__ x,
                        u16* __restrict__ xh, u16* __restrict__ xl) {
    __shared__ float Tf[64][65];
    const int t  = threadIdx.x;
    const int p0 = blockIdx.x * 64;
    const int c0 = blockIdx.y * 64;
    const int b  = blockIdx.z;

    #pragma unroll
    for (int i = 0; i < 4; ++i) {
        int cl = (t >> 4) + i * 16;
        int pl = (t & 15) * 4;
        float4 v4 = *(const float4*)&x[((size_t)(b * CDIM) + c0 + cl) * NTOK + p0 + pl];
        Tf[cl][pl + 0] = v4.x; Tf[cl][pl + 1] = v4.y;
        Tf[cl][pl + 2] = v4.z; Tf[cl][pl + 3] = v4.w;
    }
    __syncthreads();
    #pragma unroll
    for (int i = 0; i < 4; ++i) {
        int pr = (t >> 4) + i * 16;
        int c4 = (t & 15) * 4;
        u16 hs[4], ls[4];
        #pragma unroll
        for (int j = 0; j < 4; ++j) {
            float val = Tf[c4 + j][pr];
            hs[j] = f2bf(val);
            ls[j] = f2bf(val - bf2f(hs[j]));
        }
        size_t m = (size_t)(b * NTOK) + p0 + pr;
        int ksw = sw32i(p0 + pr, c0 + c4);
        *(ushort4*)&xh[m * CDIM + ksw] = make_ushort4(hs[0], hs[1], hs[2], hs[3]);
        *(ushort4*)&xl[m * CDIM + ksw] = make_ushort4(ls[0], ls[1], ls[2], ls[3]);
    }
}

// ---------------------------------------------------------------------------
// 0b: w_qkv[c][d*36+t*12+h] -> wh/wl [n'=(t*12+h)*64+d][c], SW32-swizzled.
// ---------------------------------------------------------------------------
__launch_bounds__(256)
__global__ void split_w(const float* __restrict__ w,
                        u16* __restrict__ wh, u16* __restrict__ wl) {
    __shared__ float Wf[16][148];
    const int t  = threadIdx.x;
    const int d0 = blockIdx.x * 4;
    const int c0 = blockIdx.y * 16;

    #pragma unroll
    for (int i = 0; i < 9; ++i) {
        int idx = t + i * 256;
        int cl = idx / 144;
        int nl = idx - cl * 144;
        Wf[cl][nl] = w[(size_t)(c0 + cl) * C3 + d0 * 36 + nl];
    }
    __syncthreads();
    #pragma unroll
    for (int i = 0; i < 9; ++i) {
        int idx = t + i * 256;
        int r  = idx >> 4;
        int cc = idx & 15;
        int dd = r / 36;
        int th = r - dd * 36;
        float val = Wf[cc][dd * 36 + th];
        u16 hb = f2bf(val);
        int np = th * 64 + d0 + dd;
        size_t o = (size_t)np * CDIM + sw32i(np, c0 + cc);
        wh[o] = hb;
        wl[o] = f2bf(val - bf2f(hb));
    }
}

// ---------------------------------------------------------------------------
// 0c: w_proj[k][n] -> wph/wpl [n][k] bf16 split, SW32-swizzled by row n.
// ---------------------------------------------------------------------------
__launch_bounds__(256)
__global__ void split_wp(const float* __restrict__ w,
                         u16* __restrict__ wph, u16* __restrict__ wpl) {
    __shared__ float Tf[64][65];
    const int t  = threadIdx.x;
    const int n0 = blockIdx.x * 64;
    const int k0 = blockIdx.y * 64;

    #pragma unroll
    for (int i = 0; i < 4; ++i) {
        int kl = (t >> 4) + i * 16;
        int nl = (t & 15) * 4;
        float4 v4 = *(const float4*)&w[(size_t)(k0 + kl) * CDIM + n0 + nl];
        Tf[kl][nl + 0] = v4.x; Tf[kl][nl + 1] = v4.y;
        Tf[kl][nl + 2] = v4.z; Tf[kl][nl + 3] = v4.w;
    }
    __syncthreads();
    #pragma unroll
    for (int i = 0; i < 4; ++i) {
        int nr = (t >> 4) + i * 16;
        int k4 = (t & 15) * 4;
        u16 hs[4], ls[4];
        #pragma unroll
        for (int j = 0; j < 4; ++j) {
            float val = Tf[k4 + j][nr];
            hs[j] = f2bf(val);
            ls[j] = f2bf(val - bf2f(hs[j]));
        }
        int n = n0 + nr;
        int ksw = sw32i(n, k0 + k4);
        *(ushort4*)&wph[(size_t)n * CDIM + ksw] = make_ushort4(hs[0], hs[1], hs[2], hs[3]);
        *(ushort4*)&wpl[(size_t)n * CDIM + ksw] = make_ushort4(ls[0], ls[1], ls[2], ls[3]);
    }
}

// ---------------------------------------------------------------------------
// 1: QKV GEMM bf16x3 MFMA.  Outputs: Qp packed u32 (pre-scaled 8*log2e),
//    Kh/Kl planar PLAIN [bh][p][d], Vh/Vl planar plain [bh][p][d].
// ---------------------------------------------------------------------------
__launch_bounds__(256)
__global__ void qkv_mfma(const u16* __restrict__ xh, const u16* __restrict__ xl,
                         const u16* __restrict__ wh, const u16* __restrict__ wl,
                         unsigned* __restrict__ Qp,
                         u16* __restrict__ Khg, u16* __restrict__ Klg,
                         u16* __restrict__ Vhg, u16* __restrict__ Vlg) {
    __shared__ u16 Ah[128][32];
    __shared__ u16 Al[128][32];
    __shared__ u16 Bh[128][32];
    __shared__ u16 Bl[128][32];

    const int tid = threadIdx.x;
    const int l   = tid & 63;
    const int w   = tid >> 6;
    const int lm  = l & 15;
    const int lg  = l >> 4;
    const int wr  = w >> 1;
    const int wc  = w & 1;
    const int m0  = blockIdx.x * 128;
    const int n0  = blockIdx.y * 128;
    const int b   = m0 >> 10;
    const int p0  = m0 & 1023;

    const size_t xbase = ((size_t)(b * NTOK) + p0) * CDIM;
    const int lrow = l >> 2;
    const int kq   = (l & 3) * 8;
    const int asw  = (lg ^ ((lm >> 1) & 3)) * 8;   // SW32 fragment offset

    f4v acc[4][4];
    #pragma unroll
    for (int i = 0; i < 4; ++i)
        #pragma unroll
        for (int j = 0; j < 4; ++j)
            acc[i][j] = (f4v){0.f, 0.f, 0.f, 0.f};

    for (int k0 = 0; k0 < CDIM; k0 += 32) {
        #pragma unroll
        for (int i = 0; i < 2; ++i) {
            int ch = w * 2 + i;
            int m  = ch * 16 + lrow;
            int lo = ch * 512;
            gload16(xh + xbase + (size_t)m * CDIM + k0 + kq, &Ah[0][0] + lo);
            gload16(xl + xbase + (size_t)m * CDIM + k0 + kq, &Al[0][0] + lo);
            gload16(wh + (size_t)(n0 + m) * CDIM + k0 + kq,  &Bh[0][0] + lo);
            gload16(wl + (size_t)(n0 + m) * CDIM + k0 + kq,  &Bl[0][0] + lo);
        }
        __syncthreads();

        s8v ah[4], al[4], bh[4], bl[4];
        #pragma unroll
        for (int mi = 0; mi < 4; ++mi) {
            int row = wr * 64 + mi * 16 + lm;
            ah[mi] = *(const s8v*)&Ah[row][asw];
            al[mi] = *(const s8v*)&Al[row][asw];
        }
        #pragma unroll
        for (int ni = 0; ni < 4; ++ni) {
            int row = wc * 64 + ni * 16 + lm;
            bh[ni] = *(const s8v*)&Bh[row][asw];
            bl[ni] = *(const s8v*)&Bl[row][asw];
        }
        __builtin_amdgcn_s_setprio(1);
        #pragma unroll
        for (int mi = 0; mi < 4; ++mi)
            #pragma unroll
            for (int ni = 0; ni < 4; ++ni) {
                acc[mi][ni] = MFMA16(ah[mi], bh[ni], acc[mi][ni]);
                acc[mi][ni] = MFMA16(ah[mi], bl[ni], acc[mi][ni]);
                acc[mi][ni] = MFMA16(al[mi], bh[ni], acc[mi][ni]);
            }
        __builtin_amdgcn_s_setprio(0);
        __syncthreads();
    }

    const int th = (n0 >> 6) + wc;
    const int t3 = th / 12;
    const int h  = th - t3 * 12;
    const size_t bhb = (size_t)(b * NHEAD + h) * NTOK;

    if (t3 == 0) {
        unsigned* dst = Qp + bhb * DHEAD;
        #pragma unroll
        for (int mi = 0; mi < 4; ++mi)
            #pragma unroll
            for (int r = 0; r < 4; ++r) {
                int p = p0 + wr * 64 + mi * 16 + lg * 4 + r;
                #pragma unroll
                for (int ni = 0; ni < 4; ++ni)
                    dst[(size_t)p * DHEAD + ni * 16 + lm] =
                        packsplit(acc[mi][ni][r] * (8.0f * LOG2E));
            }
    } else if (t3 == 1) {
        u16* dh = Khg + bhb * DHEAD;
        u16* dl = Klg + bhb * DHEAD;
        #pragma unroll
        for (int mi = 0; mi < 4; ++mi)
            #pragma unroll
            for (int r = 0; r < 4; ++r) {
                int p = p0 + wr * 64 + mi * 16 + lg * 4 + r;
                #pragma unroll
                for (int ni = 0; ni < 4; ++ni) {
                    int d = ni * 16 + lm;
                    float val = acc[mi][ni][r];
                    u16 hb = f2bf(val);
                    dh[(size_t)p * DHEAD + d] = hb;
                    dl[(size_t)p * DHEAD + d] = f2bf(val - bf2f(hb));
                }
            }
    } else {
        u16* dh = Vhg + bhb * DHEAD;
        u16* dl = Vlg + bhb * DHEAD;
        #pragma unroll
        for (int mi = 0; mi < 4; ++mi)
            #pragma unroll
            for (int r = 0; r < 4; ++r) {
                int p = p0 + wr * 64 + mi * 16 + lg * 4 + r;
                #pragma unroll
                for (int ni = 0; ni < 4; ++ni) {
                    int d = ni * 16 + lm;
                    float val = acc[mi][ni][r];
                    u16 hb = f2bf(val);
                    dh[(size_t)p * DHEAD + d] = hb;
                    dl[(size_t)p * DHEAD + d] = f2bf(val - bf2f(hb));
                }
            }
    }
}

// ---------------------------------------------------------------------------
// 1b: V planar [bh][p][d] -> Vt planar [bh][d][p]  (plain transpose).
// ---------------------------------------------------------------------------
__launch_bounds__(256)
__global__ void vt_split(const u16* __restrict__ Vh, const u16* __restrict__ Vl,
                         u16* __restrict__ Vth, u16* __restrict__ Vtl) {
    __shared__ u16 Th[64][72];
    __shared__ u16 Tl[64][72];
    const int t  = threadIdx.x;
    const int pt = blockIdx.x;        // 16
    const int bh = blockIdx.y;        // 96

    #pragma unroll
    for (int i = 0; i < 4; ++i) {
        int idx = t + i * 256;
        int pr  = idx >> 4;
        int c4  = (idx & 15) * 4;
        size_t src = ((size_t)bh * NTOK + pt * 64 + pr) * DHEAD + c4;
        *(ushort4*)&Th[pr][c4] = *(const ushort4*)&Vh[src];
        *(ushort4*)&Tl[pr][c4] = *(const ushort4*)&Vl[src];
    }
    __syncthreads();
    #pragma unroll
    for (int i = 0; i < 4; ++i) {
        int idx   = t + i * 256;
        int plane = idx >> 9;
        int rem   = idx & 511;
        int d     = rem >> 3;
        int gp    = rem & 7;
        u16 tmp[8];
        #pragma unroll
        for (int j = 0; j < 8; ++j)
            tmp[j] = plane ? Tl[gp * 8 + j][d] : Th[gp * 8 + j][d];
        u16* outp = plane ? Vtl : Vth;
        size_t dst = ((size_t)bh * DHEAD + d) * NTOK + pt * 64 + gp * 8;
        *(ushort4*)&outp[dst]     = make_ushort4(tmp[0], tmp[1], tmp[2], tmp[3]);
        *(ushort4*)&outp[dst + 4] = make_ushort4(tmp[4], tmp[5], tmp[6], tmp[7]);
    }
}

// ---------------------------------------------------------------------------
// 2: MFMA flash attention, barrier-free kv loop.  K and Vt fragments loaded
//    DIRECTLY from global (L1/L2-resident; XCD-grouped launch keeps each bh's
//    K/V on one XCD's L2).  P via wave-private swizzled LDS.  exp2 domain:
//    Q pre-scaled by 8*log2e.  Grid: 768 linear, bid -> (xcd, bh, qb).
// ---------------------------------------------------------------------------
__launch_bounds__(256)
__global__ void attn_mfma(const unsigned* __restrict__ Qp,
                          const u16* __restrict__ Khg, const u16* __restrict__ Klg,
                          const u16* __restrict__ Vth, const u16* __restrict__ Vtl,
                          u16* __restrict__ ctxh, u16* __restrict__ ctxl) {
    __shared__ u16 Ph[128][64];

    const int tid = threadIdx.x;
    const int l  = tid & 63;
    const int w  = tid >> 6;
    const int lm = l & 15;
    const int lg = l >> 4;

    // XCD-aware decode: consecutive bids round-robin XCDs (bid&7);
    // give each XCD 12 consecutive bh with all 8 q-blocks.
    const int bid = blockIdx.x;
    const int xcd = bid & 7;
    const int k_  = bid >> 3;               // 0..95
    const int bh  = xcd * 12 + (k_ >> 3);   // 0..95
    const int p0  = (k_ & 7) * 128;

    const unsigned* Qb = Qp + (size_t)bh * NTOK * DHEAD;
    const u16* Kb_h = Khg + (size_t)bh * NTOK * DHEAD;
    const u16* Kb_l = Klg + (size_t)bh * NTOK * DHEAD;
    const u16* Vb_h = Vth + (size_t)bh * DHEAD * NTOK;
    const u16* Vb_l = Vtl + (size_t)bh * DHEAD * NTOK;

    // Q fragments (packed, pre-scaled by 8*log2e)
    s8v qh[2][2], ql[2][2];
    #pragma unroll
    for (int t = 0; t < 2; ++t)
        #pragma unroll
        for (int kk = 0; kk < 2; ++kk) {
            const unsigned* src = Qb + (size_t)(p0 + w * 32 + t * 16 + lm) * DHEAD + kk * 32 + lg * 8;
            uint4 a0 = *(const uint4*)src;
            uint4 a1 = *(const uint4*)(src + 4);
            unpack8(a0, a1, qh[t][kk], ql[t][kk]);
        }

    f4v o[2][4];
    float mrun[2][4], lrun[2][4];
    #pragma unroll
    for (int t = 0; t < 2; ++t)
        #pragma unroll
        for (int c = 0; c < 4; ++c)
            o[t][c] = (f4v){0.f, 0.f, 0.f, 0.f};
    #pragma unroll
    for (int t = 0; t < 2; ++t)
        #pragma unroll
        for (int i = 0; i < 4; ++i) { mrun[t][i] = -3.0e38f; lrun[t][i] = 0.f; }

    // per-lane global fragment bases
    const u16* Krow_h = Kb_h + ((size_t)lm << 6) + lg * 8;   // + kv*64
    const u16* Krow_l = Kb_l + ((size_t)lm << 6) + lg * 8;
    const u16* Vrow_h = Vb_h + ((size_t)lm << 10) + lg * 8;  // + d*1024 + kv
    const u16* Vrow_l = Vb_l + ((size_t)lm << 10) + lg * 8;

    for (int kt = 0; kt < 16; ++kt) {
        const int kv0 = kt * 64;

        // ---- S = Q.K^T (bf16x3), K frags direct from global
        f4v sa[2][4];
        #pragma unroll
        for (int t = 0; t < 2; ++t)
            #pragma unroll
            for (int c = 0; c < 4; ++c)
                sa[t][c] = (f4v){0.f, 0.f, 0.f, 0.f};

        #pragma unroll
        for (int kk = 0; kk < 2; ++kk)
            #pragma unroll
            for (int c = 0; c < 4; ++c) {
                size_t off = (size_t)(kv0 + c * 16) * DHEAD + kk * 32;
                s8v kh = *(const s8v*)(Krow_h + off);
                s8v kl = *(const s8v*)(Krow_l + off);
                __builtin_amdgcn_s_setprio(1);
                #pragma unroll
                for (int t = 0; t < 2; ++t) {
                    sa[t][c] = MFMA16(qh[t][kk], kh, sa[t][c]);
                    sa[t][c] = MFMA16(qh[t][kk], kl, sa[t][c]);
                    sa[t][c] = MFMA16(ql[t][kk], kh, sa[t][c]);
                }
                __builtin_amdgcn_s_setprio(0);
            }

        // ---- online softmax (exp2 domain); P bf16-hi to swizzled LDS
        #pragma unroll
        for (int t = 0; t < 2; ++t) {
            float f_[4];
            #pragma unroll
            for (int i = 0; i < 4; ++i) {
                float mt = fmaxf(fmaxf(sa[t][0][i], sa[t][1][i]),
                                 fmaxf(sa[t][2][i], sa[t][3][i]));
                #pragma unroll
                for (int off = 1; off < 16; off <<= 1)
                    mt = fmaxf(mt, __shfl_xor(mt, off, 16));
                float mn = fmaxf(mrun[t][i], mt);
                f_[i] = exp2f(mrun[t][i] - mn);
                mrun[t][i] = mn;
            }
            #pragma unroll
            for (int i = 0; i < 4; ++i) {
                int rp = w * 32 + t * 16 + lg * 4 + i;
                float rs = 0.f;
                #pragma unroll
                for (int c = 0; c < 4; ++c) {
                    float pv = exp2f(sa[t][c][i] - mrun[t][i]);
                    rs += pv;
                    int colg = c * 2 + (lm >> 3);
                    Ph[rp][((colg ^ (rp & 7)) << 3) + (lm & 7)] = f2bf(pv);
                }
                #pragma unroll
                for (int off = 1; off < 16; off <<= 1)
                    rs += __shfl_xor(rs, off, 16);
                lrun[t][i] = lrun[t][i] * f_[i] + rs;
                #pragma unroll
                for (int c = 0; c < 4; ++c)
                    o[t][c][i] *= f_[i];
            }
        }

        // ---- O += P.V, V frags direct from global (Vt layout)
        s8v pf[2][2];
        #pragma unroll
        for (int t = 0; t < 2; ++t)
            #pragma unroll
            for (int kk = 0; kk < 2; ++kk) {
                int row = w * 32 + t * 16 + lm;
                pf[t][kk] = *(const s8v*)&Ph[row][(((kk * 4 + lg) ^ (lm & 7))) * 8];
            }
        #pragma unroll
        for (int c = 0; c < 4; ++c)
            #pragma unroll
            for (int kk = 0; kk < 2; ++kk) {
                size_t off = (size_t)(c * 16) * NTOK + kv0 + kk * 32;
                s8v vh = *(const s8v*)(Vrow_h + off);
                s8v vl = *(const s8v*)(Vrow_l + off);
                __builtin_amdgcn_s_setprio(1);
                #pragma unroll
                for (int t = 0; t < 2; ++t) {
                    o[t][c] = MFMA16(pf[t][kk], vh, o[t][c]);
                    o[t][c] = MFMA16(pf[t][kk], vl, o[t][c]);
                }
                __builtin_amdgcn_s_setprio(0);
            }
    }

    // ---- epilogue: ctx split bf16, SW32-swizzled by row m
    const int b  = bh / NHEAD;
    const int hh = bh - b * NHEAD;
    #pragma unroll
    for (int t = 0; t < 2; ++t)
        #pragma unroll
        for (int i = 0; i < 4; ++i) {
            float inv = 1.f / lrun[t][i];
            int p = p0 + w * 32 + t * 16 + lg * 4 + i;
            size_t m = (size_t)(b * NTOK) + p;
            #pragma unroll
            for (int c = 0; c < 4; ++c) {
                int col = hh * DHEAD + c * 16 + lm;
                int csw = sw32i(p, col);
                float val = o[t][c][i] * inv;
                u16 hb = f2bf(val);
                ctxh[m * CDIM + csw] = hb;
                ctxl[m * CDIM + csw] = f2bf(val - bf2f(hb));
            }
        }
}

// ---------------------------------------------------------------------------
// 3: proj GEMM bf16x3 MFMA computing out[c'][m] = sum_k W[k][c'] ctx[m][k].
// ---------------------------------------------------------------------------
__launch_bounds__(256)
__global__ void proj_mfma(const u16* __restrict__ wph, const u16* __restrict__ wpl,
                          const u16* __restrict__ cth, const u16* __restrict__ ctl,
                          float* __restrict__ out) {
    __shared__ u16 Awh[64][32];
    __shared__ u16 Awl[64][32];
    __shared__ u16 Bch[128][32];
    __shared__ u16 Bcl[128][32];

    const int tid = threadIdx.x;
    const int l   = tid & 63;
    const int w   = tid >> 6;
    const int lm  = l & 15;
    const int lg  = l >> 4;
    const int wr  = w >> 1;
    const int wc  = w & 1;
    const int c0  = blockIdx.x * 64;
    const int m0  = blockIdx.y * 128;
    const int b   = m0 >> 10;
    const int pl0 = m0 & 1023;

    const int lrow = l >> 2;
    const int kq   = (l & 3) * 8;
    const int asw  = (lg ^ ((lm >> 1) & 3)) * 8;

    f4v acc[2][4];
    #pragma unroll
    for (int i = 0; i < 2; ++i)
        #pragma unroll
        for (int j = 0; j < 4; ++j)
            acc[i][j] = (f4v){0.f, 0.f, 0.f, 0.f};

    for (int k0 = 0; k0 < CDIM; k0 += 32) {
        {
            int row = w * 16 + lrow;
            gload16(wph + (size_t)(c0 + row) * CDIM + k0 + kq, &Awh[0][0] + w * 512);
            gload16(wpl + (size_t)(c0 + row) * CDIM + k0 + kq, &Awl[0][0] + w * 512);
        }
        #pragma unroll
        for (int i = 0; i < 2; ++i) {
            int ch = w * 2 + i;
            int row = ch * 16 + lrow;
            gload16(cth + (size_t)(m0 + row) * CDIM + k0 + kq, &Bch[0][0] + ch * 512);
            gload16(ctl + (size_t)(m0 + row) * CDIM + k0 + kq, &Bcl[0][0] + ch * 512);
        }
        __syncthreads();

        s8v ah[2], al[2], bh[4], bl[4];
        #pragma unroll
        for (int mi = 0; mi < 2; ++mi) {
            int row = wr * 32 + mi * 16 + lm;
            ah[mi] = *(const s8v*)&Awh[row][asw];
            al[mi] = *(const s8v*)&Awl[row][asw];
        }
        #pragma unroll
        for (int ni = 0; ni < 4; ++ni) {
            int row = wc * 64 + ni * 16 + lm;
            bh[ni] = *(const s8v*)&Bch[row][asw];
            bl[ni] = *(const s8v*)&Bcl[row][asw];
        }
        __builtin_amdgcn_s_setprio(1);
        #pragma unroll
        for (int mi = 0; mi < 2; ++mi)
            #pragma unroll
            for (int ni = 0; ni < 4; ++ni) {
                acc[mi][ni] = MFMA16(ah[mi], bh[ni], acc[mi][ni]);
                acc[mi][ni] = MFMA16(ah[mi], bl[ni], acc[mi][ni]);
                acc[mi][ni] = MFMA16(al[mi], bh[ni], acc[mi][ni]);
            }
        __builtin_amdgcn_s_setprio(0);
        __syncthreads();
    }

    #pragma unroll
    for (int mi = 0; mi < 2; ++mi)
        #pragma unroll
        for (int r = 0; r < 4; ++r) {
            int cpr = c0 + wr * 32 + mi * 16 + lg * 4 + r;
            #pragma unroll
            for (int ni = 0; ni < 4; ++ni) {
                int p = pl0 + wc * 64 + ni * 16 + lm;
                out[((size_t)b * CDIM + cpr) * NTOK + p] = acc[mi][ni][r];
            }
        }
}

// ---------------------------------------------------------------------------
extern "C" void kernel_launch(void* const* d_in, const int* in_sizes, int n_in,
                              void* d_out, int out_size, void* d_ws, size_t ws_size,
                              hipStream_t stream) {
    (void)in_sizes; (void)n_in; (void)out_size; (void)ws_size;
    const float* x      = (const float*)d_in[0];
    const float* w_qkv  = (const float*)d_in[1];
    const float* w_proj = (const float*)d_in[2];
    float* out = (float*)d_out;

    const size_t NE = (size_t)NB * NHEAD * NTOK * DHEAD;   // 6,291,456
    char* w8 = (char*)d_ws;
    unsigned* Qp = (unsigned*)w8;                  // [0, 4NE)
    u16* Khg = (u16*)(w8 + 4 * NE);                // [4NE, 6NE)
    u16* Klg = Khg + NE;                           // [6NE, 8NE)
    u16* Vhg = (u16*)(w8 + 8 * NE);                // [8NE, 10NE)   (later ctxh)
    u16* Vlg = Vhg + NE;                           // [10NE, 12NE)  (later ctxl)
    u16* xh  = (u16*)(w8 + 12 * NE);               // [12NE, 14NE)  (later Vth)
    u16* xl  = xh + NE;                            // [14NE, 16NE)  (later Vtl)
    u16* wh  = (u16*)(w8 + 16 * NE);               // C3*CDIM u16
    u16* wl  = wh + (size_t)C3 * CDIM;
    // aliases (lifetimes disjoint; peak footprint 16NE + 7.08MB = 107.75 MB):
    u16* Vth  = xh;   u16* Vtl  = xl;
    u16* ctxh = Vhg;  u16* ctxl = Vlg;
    u16* wph  = wh;   u16* wpl  = wh + (size_t)CDIM * CDIM;

    split_x <<<dim3(16, 12, 8), 256, 0, stream>>>(x, xh, xl);
    split_w <<<dim3(16, 48),    256, 0, stream>>>(w_qkv, wh, wl);
    qkv_mfma<<<dim3(64, 18),    256, 0, stream>>>(xh, xl, wh, wl, Qp, Khg, Klg, Vhg, Vlg);
    split_wp<<<dim3(12, 12),    256, 0, stream>>>(w_proj, wph, wpl);
    vt_split<<<dim3(16, 96),    256, 0, stream>>>(Vhg, Vlg, Vth, Vtl);
    attn_mfma<<<dim3(768),      256, 0, stream>>>(Qp, Khg, Klg, Vth, Vtl, ctxh, ctxl);
    proj_mfma<<<dim3(12, 64),   256, 0, stream>>>(wph, wpl, ctxh, ctxl, out);
}

// Round 7
// 381.695 us; speedup vs baseline: 1.2380x; 1.2380x over previous
//
#include <hip/hip_runtime.h>

#define NB    8
#define CDIM  768
#define NTOK  1024
#define NHEAD 12
#define DHEAD 64
#define C3    2304

typedef unsigned short u16;
typedef short  s8v __attribute__((ext_vector_type(8)));
typedef float  f4v __attribute__((ext_vector_type(4)));

#define MFMA16(a, b, c) __builtin_amdgcn_mfma_f32_16x16x32_bf16((a), (b), (c), 0, 0, 0)
#define LOG2E 1.4426950408889634f

static __device__ __forceinline__ u16 f2bf(float f) {
    unsigned u = __float_as_uint(f);
    u += 0x7fffu + ((u >> 16) & 1u);
    return (u16)(u >> 16);
}
static __device__ __forceinline__ float bf2f(u16 b) {
    return __uint_as_float(((unsigned)b) << 16);
}
static __device__ __forceinline__ unsigned packsplit(float x) {
    u16 h = f2bf(x);
    u16 l = f2bf(x - bf2f(h));
    return (unsigned)h | ((unsigned)l << 16);
}
static __device__ __forceinline__ void unpack8(uint4 a, uint4 b, s8v& h, s8v& l) {
    h = (s8v){(short)a.x, (short)a.y, (short)a.z, (short)a.w,
              (short)b.x, (short)b.y, (short)b.z, (short)b.w};
    l = (s8v){(short)(a.x >> 16), (short)(a.y >> 16), (short)(a.z >> 16), (short)(a.w >> 16),
              (short)(b.x >> 16), (short)(b.y >> 16), (short)(b.z >> 16), (short)(b.w >> 16)};
}
// SW32: swizzle for K-innermost bf16 arrays consumed as [row][32] BK=32 LDS tiles
static __device__ __forceinline__ int sw32i(int row, int k) {
    int g = (k >> 3) & 3;
    int gs = g ^ ((row >> 1) & 3);
    return (k & ~31) + (gs << 3) + (k & 7);
}
// async global->LDS 16B/lane: dst is WAVE-UNIFORM base (HW adds lane*16)
static __device__ __forceinline__ void gload16(const u16* gsrc, u16* ldst) {
    __builtin_amdgcn_global_load_lds(
        (const __attribute__((address_space(1))) void*)gsrc,
        (__attribute__((address_space(3))) void*)ldst, 16, 0, 0);
}

// ---------------------------------------------------------------------------
// 0a: x[b][c][p] fp32 -> xh/xl [b*p][c] bf16 split, SW32-swizzled by row m.
// ---------------------------------------------------------------------------
__launch_bounds__(256)
__global__ void split_x(const float* __restrict__ x,
                        u16* __restrict__ xh, u16* __restrict__ xl) {
    __shared__ float Tf[64][65];
    const int t  = threadIdx.x;
    const int p0 = blockIdx.x * 64;
    const int c0 = blockIdx.y * 64;
    const int b  = blockIdx.z;

    #pragma unroll
    for (int i = 0; i < 4; ++i) {
        int cl = (t >> 4) + i * 16;
        int pl = (t & 15) * 4;
        float4 v4 = *(const float4*)&x[((size_t)(b * CDIM) + c0 + cl) * NTOK + p0 + pl];
        Tf[cl][pl + 0] = v4.x; Tf[cl][pl + 1] = v4.y;
        Tf[cl][pl + 2] = v4.z; Tf[cl][pl + 3] = v4.w;
    }
    __syncthreads();
    #pragma unroll
    for (int i = 0; i < 4; ++i) {
        int pr = (t >> 4) + i * 16;
        int c4 = (t & 15) * 4;
        u16 hs[4], ls[4];
        #pragma unroll
        for (int j = 0; j < 4; ++j) {
            float val = Tf[c4 + j][pr];
            hs[j] = f2bf(val);
            ls[j] = f2bf(val - bf2f(hs[j]));
        }
        size_t m = (size_t)(b * NTOK) + p0 + pr;
        int ksw = sw32i(p0 + pr, c0 + c4);
        *(ushort4*)&xh[m * CDIM + ksw] = make_ushort4(hs[0], hs[1], hs[2], hs[3]);
        *(ushort4*)&xl[m * CDIM + ksw] = make_ushort4(ls[0], ls[1], ls[2], ls[3]);
    }
}

// ---------------------------------------------------------------------------
// 0b: w_qkv[c][d*36+t*12+h] -> wh/wl [n'=(t*12+h)*64+d][c], SW32-swizzled.
// ---------------------------------------------------------------------------
__launch_bounds__(256)
__global__ void split_w(const float* __restrict__ w,
                        u16* __restrict__ wh, u16* __restrict__ wl) {
    __shared__ float Wf[16][148];
    const int t  = threadIdx.x;
    const int d0 = blockIdx.x * 4;
    const int c0 = blockIdx.y * 16;

    #pragma unroll
    for (int i = 0; i < 9; ++i) {
        int idx = t + i * 256;
        int cl = idx / 144;
        int nl = idx - cl * 144;
        Wf[cl][nl] = w[(size_t)(c0 + cl) * C3 + d0 * 36 + nl];
    }
    __syncthreads();
    #pragma unroll
    for (int i = 0; i < 9; ++i) {
        int idx = t + i * 256;
        int r  = idx >> 4;
        int cc = idx & 15;
        int dd = r / 36;
        int th = r - dd * 36;
        float val = Wf[cc][dd * 36 + th];
        u16 hb = f2bf(val);
        int np = th * 64 + d0 + dd;
        size_t o = (size_t)np * CDIM + sw32i(np, c0 + cc);
        wh[o] = hb;
        wl[o] = f2bf(val - bf2f(hb));
    }
}

// ---------------------------------------------------------------------------
// 0c: w_proj[k][n] -> wph/wpl [n][k] bf16 split, SW32-swizzled by row n.
//     (launched AFTER qkv_mfma: aliases the then-dead wh/wl region)
// ---------------------------------------------------------------------------
__launch_bounds__(256)
__global__ void split_wp(const float* __restrict__ w,
                         u16* __restrict__ wph, u16* __restrict__ wpl) {
    __shared__ float Tf[64][65];
    const int t  = threadIdx.x;
    const int n0 = blockIdx.x * 64;
    const int k0 = blockIdx.y * 64;

    #pragma unroll
    for (int i = 0; i < 4; ++i) {
        int kl = (t >> 4) + i * 16;
        int nl = (t & 15) * 4;
        float4 v4 = *(const float4*)&w[(size_t)(k0 + kl) * CDIM + n0 + nl];
        Tf[kl][nl + 0] = v4.x; Tf[kl][nl + 1] = v4.y;
        Tf[kl][nl + 2] = v4.z; Tf[kl][nl + 3] = v4.w;
    }
    __syncthreads();
    #pragma unroll
    for (int i = 0; i < 4; ++i) {
        int nr = (t >> 4) + i * 16;
        int k4 = (t & 15) * 4;
        u16 hs[4], ls[4];
        #pragma unroll
        for (int j = 0; j < 4; ++j) {
            float val = Tf[k4 + j][nr];
            hs[j] = f2bf(val);
            ls[j] = f2bf(val - bf2f(hs[j]));
        }
        int n = n0 + nr;
        int ksw = sw32i(n, k0 + k4);
        *(ushort4*)&wph[(size_t)n * CDIM + ksw] = make_ushort4(hs[0], hs[1], hs[2], hs[3]);
        *(ushort4*)&wpl[(size_t)n * CDIM + ksw] = make_ushort4(ls[0], ls[1], ls[2], ls[3]);
    }
}

// ---------------------------------------------------------------------------
// 1: QKV GEMM bf16x3 MFMA.  Outputs: Qp packed u32 (pre-scaled 8*log2e),
//    Kh/Kl planar SW64-swizzled [bh][p][d], Vh/Vl planar plain [bh][p][d].
// ---------------------------------------------------------------------------
__launch_bounds__(256)
__global__ void qkv_mfma(const u16* __restrict__ xh, const u16* __restrict__ xl,
                         const u16* __restrict__ wh, const u16* __restrict__ wl,
                         unsigned* __restrict__ Qp,
                         u16* __restrict__ Khg, u16* __restrict__ Klg,
                         u16* __restrict__ Vhg, u16* __restrict__ Vlg) {
    __shared__ u16 Ah[128][32];
    __shared__ u16 Al[128][32];
    __shared__ u16 Bh[128][32];
    __shared__ u16 Bl[128][32];

    const int tid = threadIdx.x;
    const int l   = tid & 63;
    const int w   = tid >> 6;
    const int lm  = l & 15;
    const int lg  = l >> 4;
    const int wr  = w >> 1;
    const int wc  = w & 1;
    const int m0  = blockIdx.x * 128;
    const int n0  = blockIdx.y * 128;
    const int b   = m0 >> 10;
    const int p0  = m0 & 1023;

    const size_t xbase = ((size_t)(b * NTOK) + p0) * CDIM;
    const int lrow = l >> 2;
    const int kq   = (l & 3) * 8;
    const int asw  = (lg ^ ((lm >> 1) & 3)) * 8;   // SW32 fragment offset

    f4v acc[4][4];
    #pragma unroll
    for (int i = 0; i < 4; ++i)
        #pragma unroll
        for (int j = 0; j < 4; ++j)
            acc[i][j] = (f4v){0.f, 0.f, 0.f, 0.f};

    for (int k0 = 0; k0 < CDIM; k0 += 32) {
        #pragma unroll
        for (int i = 0; i < 2; ++i) {
            int ch = w * 2 + i;
            int m  = ch * 16 + lrow;
            int lo = ch * 512;
            gload16(xh + xbase + (size_t)m * CDIM + k0 + kq, &Ah[0][0] + lo);
            gload16(xl + xbase + (size_t)m * CDIM + k0 + kq, &Al[0][0] + lo);
            gload16(wh + (size_t)(n0 + m) * CDIM + k0 + kq,  &Bh[0][0] + lo);
            gload16(wl + (size_t)(n0 + m) * CDIM + k0 + kq,  &Bl[0][0] + lo);
        }
        __syncthreads();

        s8v ah[4], al[4], bh[4], bl[4];
        #pragma unroll
        for (int mi = 0; mi < 4; ++mi) {
            int row = wr * 64 + mi * 16 + lm;
            ah[mi] = *(const s8v*)&Ah[row][asw];
            al[mi] = *(const s8v*)&Al[row][asw];
        }
        #pragma unroll
        for (int ni = 0; ni < 4; ++ni) {
            int row = wc * 64 + ni * 16 + lm;
            bh[ni] = *(const s8v*)&Bh[row][asw];
            bl[ni] = *(const s8v*)&Bl[row][asw];
        }
        __builtin_amdgcn_s_setprio(1);
        #pragma unroll
        for (int mi = 0; mi < 4; ++mi)
            #pragma unroll
            for (int ni = 0; ni < 4; ++ni) {
                acc[mi][ni] = MFMA16(ah[mi], bh[ni], acc[mi][ni]);
                acc[mi][ni] = MFMA16(ah[mi], bl[ni], acc[mi][ni]);
                acc[mi][ni] = MFMA16(al[mi], bh[ni], acc[mi][ni]);
            }
        __builtin_amdgcn_s_setprio(0);
        __syncthreads();
    }

    const int th = (n0 >> 6) + wc;
    const int t3 = th / 12;
    const int h  = th - t3 * 12;
    const size_t bhb = (size_t)(b * NHEAD + h) * NTOK;

    if (t3 == 0) {
        unsigned* dst = Qp + bhb * DHEAD;
        #pragma unroll
        for (int mi = 0; mi < 4; ++mi)
            #pragma unroll
            for (int r = 0; r < 4; ++r) {
                int p = p0 + wr * 64 + mi * 16 + lg * 4 + r;
                #pragma unroll
                for (int ni = 0; ni < 4; ++ni)
                    dst[(size_t)p * DHEAD + ni * 16 + lm] =
                        packsplit(acc[mi][ni][r] * (8.0f * LOG2E));
            }
    } else if (t3 == 1) {
        u16* dh = Khg + bhb * DHEAD;
        u16* dl = Klg + bhb * DHEAD;
        #pragma unroll
        for (int mi = 0; mi < 4; ++mi)
            #pragma unroll
            for (int r = 0; r < 4; ++r) {
                int p = p0 + wr * 64 + mi * 16 + lg * 4 + r;
                #pragma unroll
                for (int ni = 0; ni < 4; ++ni) {
                    int d = ni * 16 + lm;
                    int dsw = (((d >> 3) ^ (p & 7)) << 3) | (d & 7);   // SW64
                    float val = acc[mi][ni][r];
                    u16 hb = f2bf(val);
                    dh[(size_t)p * DHEAD + dsw] = hb;
                    dl[(size_t)p * DHEAD + dsw] = f2bf(val - bf2f(hb));
                }
            }
    } else {
        u16* dh = Vhg + bhb * DHEAD;
        u16* dl = Vlg + bhb * DHEAD;
        #pragma unroll
        for (int mi = 0; mi < 4; ++mi)
            #pragma unroll
            for (int r = 0; r < 4; ++r) {
                int p = p0 + wr * 64 + mi * 16 + lg * 4 + r;
                #pragma unroll
                for (int ni = 0; ni < 4; ++ni) {
                    int d = ni * 16 + lm;
                    float val = acc[mi][ni][r];
                    u16 hb = f2bf(val);
                    dh[(size_t)p * DHEAD + d] = hb;
                    dl[(size_t)p * DHEAD + d] = f2bf(val - bf2f(hb));
                }
            }
    }
}

// ---------------------------------------------------------------------------
// 1b: V planar [bh][p][d] -> Vt planar [bh][d][p], SW64-swizzled by d within
//     each 64-p window (pre-swizzled source for gload_lds, m173 pattern).
// ---------------------------------------------------------------------------
__launch_bounds__(256)
__global__ void vt_split(const u16* __restrict__ Vh, const u16* __restrict__ Vl,
                         u16* __restrict__ Vth, u16* __restrict__ Vtl) {
    __shared__ u16 Th[64][72];
    __shared__ u16 Tl[64][72];
    const int t  = threadIdx.x;
    const int pt = blockIdx.x;        // 16
    const int bh = blockIdx.y;        // 96

    #pragma unroll
    for (int i = 0; i < 4; ++i) {
        int idx = t + i * 256;
        int pr  = idx >> 4;
        int c4  = (idx & 15) * 4;
        size_t src = ((size_t)bh * NTOK + pt * 64 + pr) * DHEAD + c4;
        *(ushort4*)&Th[pr][c4] = *(const ushort4*)&Vh[src];
        *(ushort4*)&Tl[pr][c4] = *(const ushort4*)&Vl[src];
    }
    __syncthreads();
    #pragma unroll
    for (int i = 0; i < 4; ++i) {
        int idx   = t + i * 256;
        int plane = idx >> 9;
        int rem   = idx & 511;
        int d     = rem >> 3;
        int gp    = rem & 7;          // stored group position
        int gs    = gp ^ (d & 7);     // source p-group (SW64 pre-swizzle)
        u16 tmp[8];
        #pragma unroll
        for (int j = 0; j < 8; ++j)
            tmp[j] = plane ? Tl[gs * 8 + j][d] : Th[gs * 8 + j][d];
        u16* outp = plane ? Vtl : Vth;
        size_t dst = ((size_t)bh * DHEAD + d) * NTOK + pt * 64 + gp * 8;
        *(ushort4*)&outp[dst]     = make_ushort4(tmp[0], tmp[1], tmp[2], tmp[3]);
        *(ushort4*)&outp[dst + 4] = make_ushort4(tmp[4], tmp[5], tmp[6], tmp[7]);
    }
}

// ---------------------------------------------------------------------------
// 2: MFMA flash attention (LDS-staged, conflict-free swizzles, XCD-grouped
//    grid, exp2-domain softmax).  Block = 4 waves, QBLK=128, KVBLK=64.
// ---------------------------------------------------------------------------
__launch_bounds__(256)
__global__ void attn_mfma(const unsigned* __restrict__ Qp,
                          const u16* __restrict__ Khg, const u16* __restrict__ Klg,
                          const u16* __restrict__ Vth, const u16* __restrict__ Vtl,
                          u16* __restrict__ ctxh, u16* __restrict__ ctxl) {
    __shared__ u16 Kh[64][64];
    __shared__ u16 Kl[64][64];
    __shared__ u16 Vh[64][64];
    __shared__ u16 Vl[64][64];
    __shared__ u16 Ph[128][64];

    const int tid = threadIdx.x;
    const int l  = tid & 63;
    const int w  = tid >> 6;
    const int lm = l & 15;
    const int lg = l >> 4;

    // XCD-aware decode: bid&7 = xcd; each XCD gets 12 bh with all 8 q-blocks.
    const int bid = blockIdx.x;
    const int xcd = bid & 7;
    const int k_  = bid >> 3;               // 0..95
    const int bh  = xcd * 12 + (k_ >> 3);   // 0..95
    const int p0  = (k_ & 7) * 128;

    const unsigned* Qb = Qp + (size_t)bh * NTOK * DHEAD;
    const u16* Kb_h = Khg + (size_t)bh * NTOK * DHEAD;
    const u16* Kb_l = Klg + (size_t)bh * NTOK * DHEAD;
    const u16* Vb_h = Vth + (size_t)bh * DHEAD * NTOK;
    const u16* Vb_l = Vtl + (size_t)bh * DHEAD * NTOK;

    // Q fragments (packed, pre-scaled by 8*log2e)
    s8v qh[2][2], ql[2][2];
    #pragma unroll
    for (int t = 0; t < 2; ++t)
        #pragma unroll
        for (int kk = 0; kk < 2; ++kk) {
            const unsigned* src = Qb + (size_t)(p0 + w * 32 + t * 16 + lm) * DHEAD + kk * 32 + lg * 8;
            uint4 a0 = *(const uint4*)src;
            uint4 a1 = *(const uint4*)(src + 4);
            unpack8(a0, a1, qh[t][kk], ql[t][kk]);
        }

    f4v o[2][4];
    float mrun[2][4], lrun[2][4];
    #pragma unroll
    for (int t = 0; t < 2; ++t)
        #pragma unroll
        for (int c = 0; c < 4; ++c)
            o[t][c] = (f4v){0.f, 0.f, 0.f, 0.f};
    #pragma unroll
    for (int t = 0; t < 2; ++t)
        #pragma unroll
        for (int i = 0; i < 4; ++i) { mrun[t][i] = -3.0e38f; lrun[t][i] = 0.f; }

    const int fsw = (l & 7) * 8;      // 16B block within a 128B row for DMA
    const int r8  = l >> 3;           // row-in-chunk (8 rows of 128B per 1KB chunk)

    for (int kt = 0; kt < 16; ++kt) {
        __syncthreads();
        // stage K(h,l) and Vt(h,l): 8 chunks each, wave w does chunks w*2,w*2+1
        #pragma unroll
        for (int i = 0; i < 2; ++i) {
            int ch = w * 2 + i;
            int lo = ch * 512;
            size_t krow = (size_t)(kt * 64 + ch * 8 + r8) * DHEAD + fsw;
            gload16(Kb_h + krow, &Kh[0][0] + lo);
            gload16(Kb_l + krow, &Kl[0][0] + lo);
            size_t vrow = (size_t)(ch * 8 + r8) * NTOK + kt * 64 + fsw;
            gload16(Vb_h + vrow, &Vh[0][0] + lo);
            gload16(Vb_l + vrow, &Vl[0][0] + lo);
        }
        __syncthreads();

        // S = Q.K^T (bf16x3)
        f4v sa[2][4];
        #pragma unroll
        for (int t = 0; t < 2; ++t)
            #pragma unroll
            for (int c = 0; c < 4; ++c)
                sa[t][c] = (f4v){0.f, 0.f, 0.f, 0.f};

        #pragma unroll
        for (int kk = 0; kk < 2; ++kk)
            #pragma unroll
            for (int c = 0; c < 4; ++c) {
                int row = c * 16 + lm;
                int off = (((kk * 4 + lg) ^ (lm & 7))) * 8;   // SW64
                s8v kh = *(const s8v*)&Kh[row][off];
                s8v kl = *(const s8v*)&Kl[row][off];
                __builtin_amdgcn_s_setprio(1);
                #pragma unroll
                for (int t = 0; t < 2; ++t) {
                    sa[t][c] = MFMA16(qh[t][kk], kh, sa[t][c]);
                    sa[t][c] = MFMA16(qh[t][kk], kl, sa[t][c]);
                    sa[t][c] = MFMA16(ql[t][kk], kh, sa[t][c]);
                }
                __builtin_amdgcn_s_setprio(0);
            }

        // online softmax (exp2 domain); P bf16-hi to swizzled wave-private LDS
        #pragma unroll
        for (int t = 0; t < 2; ++t) {
            float f_[4];
            #pragma unroll
            for (int i = 0; i < 4; ++i) {
                float mt = fmaxf(fmaxf(sa[t][0][i], sa[t][1][i]),
                                 fmaxf(sa[t][2][i], sa[t][3][i]));
                #pragma unroll
                for (int off = 1; off < 16; off <<= 1)
                    mt = fmaxf(mt, __shfl_xor(mt, off, 16));
                float mn = fmaxf(mrun[t][i], mt);
                f_[i] = exp2f(mrun[t][i] - mn);
                mrun[t][i] = mn;
            }
            #pragma unroll
            for (int i = 0; i < 4; ++i) {
                int rp = w * 32 + t * 16 + lg * 4 + i;
                float rs = 0.f;
                #pragma unroll
                for (int c = 0; c < 4; ++c) {
                    float pv = exp2f(sa[t][c][i] - mrun[t][i]);
                    rs += pv;
                    int colg = c * 2 + (lm >> 3);
                    Ph[rp][((colg ^ (rp & 7)) << 3) + (lm & 7)] = f2bf(pv);
                }
                #pragma unroll
                for (int off = 1; off < 16; off <<= 1)
                    rs += __shfl_xor(rs, off, 16);
                lrun[t][i] = lrun[t][i] * f_[i] + rs;
                #pragma unroll
                for (int c = 0; c < 4; ++c)
                    o[t][c][i] *= f_[i];
            }
        }

        // O += P.V  (P rows are wave-private; compiler handles lgkmcnt)
        s8v pf[2][2];
        #pragma unroll
        for (int t = 0; t < 2; ++t)
            #pragma unroll
            for (int kk = 0; kk < 2; ++kk) {
                int row = w * 32 + t * 16 + lm;
                pf[t][kk] = *(const s8v*)&Ph[row][(((kk * 4 + lg) ^ (lm & 7))) * 8];
            }
        #pragma unroll
        for (int c = 0; c < 4; ++c)
            #pragma unroll
            for (int kk = 0; kk < 2; ++kk) {
                int row = c * 16 + lm;
                int off = (((kk * 4 + lg) ^ (lm & 7))) * 8;
                s8v vh = *(const s8v*)&Vh[row][off];
                s8v vl = *(const s8v*)&Vl[row][off];
                __builtin_amdgcn_s_setprio(1);
                #pragma unroll
                for (int t = 0; t < 2; ++t) {
                    o[t][c] = MFMA16(pf[t][kk], vh, o[t][c]);
                    o[t][c] = MFMA16(pf[t][kk], vl, o[t][c]);
                }
                __builtin_amdgcn_s_setprio(0);
            }
    }

    // epilogue: ctx split bf16, SW32-swizzled by row m
    const int b  = bh / NHEAD;
    const int hh = bh - b * NHEAD;
    #pragma unroll
    for (int t = 0; t < 2; ++t)
        #pragma unroll
        for (int i = 0; i < 4; ++i) {
            float inv = 1.f / lrun[t][i];
            int p = p0 + w * 32 + t * 16 + lg * 4 + i;
            size_t m = (size_t)(b * NTOK) + p;
            #pragma unroll
            for (int c = 0; c < 4; ++c) {
                int col = hh * DHEAD + c * 16 + lm;
                int csw = sw32i(p, col);
                float val = o[t][c][i] * inv;
                u16 hb = f2bf(val);
                ctxh[m * CDIM + csw] = hb;
                ctxl[m * CDIM + csw] = f2bf(val - bf2f(hb));
            }
        }
}

// ---------------------------------------------------------------------------
// 3: proj GEMM bf16x3 MFMA computing out[c'][m] = sum_k W[k][c'] ctx[m][k].
// ---------------------------------------------------------------------------
__launch_bounds__(256)
__global__ void proj_mfma(const u16* __restrict__ wph, const u16* __restrict__ wpl,
                          const u16* __restrict__ cth, const u16* __restrict__ ctl,
                          float* __restrict__ out) {
    __shared__ u16 Awh[64][32];
    __shared__ u16 Awl[64][32];
    __shared__ u16 Bch[128][32];
    __shared__ u16 Bcl[128][32];

    const int tid = threadIdx.x;
    const int l   = tid & 63;
    const int w   = tid >> 6;
    const int lm  = l & 15;
    const int lg  = l >> 4;
    const int wr  = w >> 1;
    const int wc  = w & 1;
    const int c0  = blockIdx.x * 64;
    const int m0  = blockIdx.y * 128;
    const int b   = m0 >> 10;
    const int pl0 = m0 & 1023;

    const int lrow = l >> 2;
    const int kq   = (l & 3) * 8;
    const int asw  = (lg ^ ((lm >> 1) & 3)) * 8;

    f4v acc[2][4];
    #pragma unroll
    for (int i = 0; i < 2; ++i)
        #pragma unroll
        for (int j = 0; j < 4; ++j)
            acc[i][j] = (f4v){0.f, 0.f, 0.f, 0.f};

    for (int k0 = 0; k0 < CDIM; k0 += 32) {
        {
            int row = w * 16 + lrow;
            gload16(wph + (size_t)(c0 + row) * CDIM + k0 + kq, &Awh[0][0] + w * 512);
            gload16(wpl + (size_t)(c0 + row) * CDIM + k0 + kq, &Awl[0][0] + w * 512);
        }
        #pragma unroll
        for (int i = 0; i < 2; ++i) {
            int ch = w * 2 + i;
            int row = ch * 16 + lrow;
            gload16(cth + (size_t)(m0 + row) * CDIM + k0 + kq, &Bch[0][0] + ch * 512);
            gload16(ctl + (size_t)(m0 + row) * CDIM + k0 + kq, &Bcl[0][0] + ch * 512);
        }
        __syncthreads();

        s8v ah[2], al[2], bh[4], bl[4];
        #pragma unroll
        for (int mi = 0; mi < 2; ++mi) {
            int row = wr * 32 + mi * 16 + lm;
            ah[mi] = *(const s8v*)&Awh[row][asw];
            al[mi] = *(const s8v*)&Awl[row][asw];
        }
        #pragma unroll
        for (int ni = 0; ni < 4; ++ni) {
            int row = wc * 64 + ni * 16 + lm;
            bh[ni] = *(const s8v*)&Bch[row][asw];
            bl[ni] = *(const s8v*)&Bcl[row][asw];
        }
        __builtin_amdgcn_s_setprio(1);
        #pragma unroll
        for (int mi = 0; mi < 2; ++mi)
            #pragma unroll
            for (int ni = 0; ni < 4; ++ni) {
                acc[mi][ni] = MFMA16(ah[mi], bh[ni], acc[mi][ni]);
                acc[mi][ni] = MFMA16(ah[mi], bl[ni], acc[mi][ni]);
                acc[mi][ni] = MFMA16(al[mi], bh[ni], acc[mi][ni]);
            }
        __builtin_amdgcn_s_setprio(0);
        __syncthreads();
    }

    #pragma unroll
    for (int mi = 0; mi < 2; ++mi)
        #pragma unroll
        for (int r = 0; r < 4; ++r) {
            int cpr = c0 + wr * 32 + mi * 16 + lg * 4 + r;
            #pragma unroll
            for (int ni = 0; ni < 4; ++ni) {
                int p = pl0 + wc * 64 + ni * 16 + lm;
                out[((size_t)b * CDIM + cpr) * NTOK + p] = acc[mi][ni][r];
            }
        }
}

// ---------------------------------------------------------------------------
extern "C" void kernel_launch(void* const* d_in, const int* in_sizes, int n_in,
                              void* d_out, int out_size, void* d_ws, size_t ws_size,
                              hipStream_t stream) {
    (void)in_sizes; (void)n_in; (void)out_size; (void)ws_size;
    const float* x      = (const float*)d_in[0];
    const float* w_qkv  = (const float*)d_in[1];
    const float* w_proj = (const float*)d_in[2];
    float* out = (float*)d_out;

    const size_t NE = (size_t)NB * NHEAD * NTOK * DHEAD;   // 6,291,456
    char* w8 = (char*)d_ws;
    unsigned* Qp = (unsigned*)w8;                  // [0, 4NE)
    u16* Khg = (u16*)(w8 + 4 * NE);                // [4NE, 6NE)
    u16* Klg = Khg + NE;                           // [6NE, 8NE)
    u16* Vhg = (u16*)(w8 + 8 * NE);                // [8NE, 10NE)   (later ctxh)
    u16* Vlg = Vhg + NE;                           // [10NE, 12NE)  (later ctxl)
    u16* xh  = (u16*)(w8 + 12 * NE);               // [12NE, 14NE)  (later Vth)
    u16* xl  = xh + NE;                            // [14NE, 16NE)  (later Vtl)
    u16* wh  = (u16*)(w8 + 16 * NE);               // C3*CDIM u16
    u16* wl  = wh + (size_t)C3 * CDIM;
    // aliases (lifetimes disjoint; peak footprint 16NE + 7.08MB = 107.75 MB):
    u16* Vth  = xh;   u16* Vtl  = xl;
    u16* ctxh = Vhg;  u16* ctxl = Vlg;
    u16* wph  = wh;   u16* wpl  = wh + (size_t)CDIM * CDIM;

    split_x <<<dim3(16, 12, 8), 256, 0, stream>>>(x, xh, xl);
    split_w <<<dim3(16, 48),    256, 0, stream>>>(w_qkv, wh, wl);
    qkv_mfma<<<dim3(64, 18),    256, 0, stream>>>(xh, xl, wh, wl, Qp, Khg, Klg, Vhg, Vlg);
    split_wp<<<dim3(12, 12),    256, 0, stream>>>(w_proj, wph, wpl);
    vt_split<<<dim3(16, 96),    256, 0, stream>>>(Vhg, Vlg, Vth, Vtl);
    attn_mfma<<<dim3(768),      256, 0, stream>>>(Qp, Khg, Klg, Vth, Vtl, ctxh, ctxl);
    proj_mfma<<<dim3(12, 64),   256, 0, stream>>>(wph, wpl, ctxh, ctxl, out);
}

// Round 9
// 371.509 us; speedup vs baseline: 1.2720x; 1.0274x over previous
//
#include <hip/hip_runtime.h>

#define NB    8
#define CDIM  768
#define NTOK  1024
#define NHEAD 12
#define DHEAD 64
#define C3    2304

typedef unsigned short u16;
typedef short  s8v __attribute__((ext_vector_type(8)));
typedef float  f4v __attribute__((ext_vector_type(4)));

#define MFMA16(a, b, c) __builtin_amdgcn_mfma_f32_16x16x32_bf16((a), (b), (c), 0, 0, 0)
#define LOG2E 1.4426950408889634f

static __device__ __forceinline__ u16 f2bf(float f) {
    unsigned u = __float_as_uint(f);
    u += 0x7fffu + ((u >> 16) & 1u);
    return (u16)(u >> 16);
}
static __device__ __forceinline__ float bf2f(u16 b) {
    return __uint_as_float(((unsigned)b) << 16);
}
static __device__ __forceinline__ unsigned packsplit(float x) {
    u16 h = f2bf(x);
    u16 l = f2bf(x - bf2f(h));
    return (unsigned)h | ((unsigned)l << 16);
}
static __device__ __forceinline__ void unpack8(uint4 a, uint4 b, s8v& h, s8v& l) {
    h = (s8v){(short)a.x, (short)a.y, (short)a.z, (short)a.w,
              (short)b.x, (short)b.y, (short)b.z, (short)b.w};
    l = (s8v){(short)(a.x >> 16), (short)(a.y >> 16), (short)(a.z >> 16), (short)(a.w >> 16),
              (short)(b.x >> 16), (short)(b.y >> 16), (short)(b.z >> 16), (short)(b.w >> 16)};
}
// SW32: swizzle for K-innermost bf16 arrays consumed as [row][32] BK=32 LDS tiles
static __device__ __forceinline__ int sw32i(int row, int k) {
    int g = (k >> 3) & 3;
    int gs = g ^ ((row >> 1) & 3);
    return (k & ~31) + (gs << 3) + (k & 7);
}
// async global->LDS 16B/lane: dst is WAVE-UNIFORM base (HW adds lane*16)
static __device__ __forceinline__ void gload16(const u16* gsrc, u16* ldst) {
    __builtin_amdgcn_global_load_lds(
        (const __attribute__((address_space(1))) void*)gsrc,
        (__attribute__((address_space(3))) void*)ldst, 16, 0, 0);
}

// ---------------------------------------------------------------------------
// 0a: x[b][c][p] fp32 -> xh/xl [b*p][c] bf16 split, SW32-swizzled by row m.
// ---------------------------------------------------------------------------
__launch_bounds__(256)
__global__ void split_x(const float* __restrict__ x,
                        u16* __restrict__ xh, u16* __restrict__ xl) {
    __shared__ float Tf[64][65];
    const int t  = threadIdx.x;
    const int p0 = blockIdx.x * 64;
    const int c0 = blockIdx.y * 64;
    const int b  = blockIdx.z;

    #pragma unroll
    for (int i = 0; i < 4; ++i) {
        int cl = (t >> 4) + i * 16;
        int pl = (t & 15) * 4;
        float4 v4 = *(const float4*)&x[((size_t)(b * CDIM) + c0 + cl) * NTOK + p0 + pl];
        Tf[cl][pl + 0] = v4.x; Tf[cl][pl + 1] = v4.y;
        Tf[cl][pl + 2] = v4.z; Tf[cl][pl + 3] = v4.w;
    }
    __syncthreads();
    #pragma unroll
    for (int i = 0; i < 4; ++i) {
        int pr = (t >> 4) + i * 16;
        int c4 = (t & 15) * 4;
        u16 hs[4], ls[4];
        #pragma unroll
        for (int j = 0; j < 4; ++j) {
            float val = Tf[c4 + j][pr];
            hs[j] = f2bf(val);
            ls[j] = f2bf(val - bf2f(hs[j]));
        }
        size_t m = (size_t)(b * NTOK) + p0 + pr;
        int ksw = sw32i(p0 + pr, c0 + c4);
        *(ushort4*)&xh[m * CDIM + ksw] = make_ushort4(hs[0], hs[1], hs[2], hs[3]);
        *(ushort4*)&xl[m * CDIM + ksw] = make_ushort4(ls[0], ls[1], ls[2], ls[3]);
    }
}

// ---------------------------------------------------------------------------
// 0b: w_qkv[c][d*36+t*12+h] -> wh/wl [n'=(t*12+h)*64+d][c], SW32-swizzled.
// ---------------------------------------------------------------------------
__launch_bounds__(256)
__global__ void split_w(const float* __restrict__ w,
                        u16* __restrict__ wh, u16* __restrict__ wl) {
    __shared__ float Wf[16][148];
    const int t  = threadIdx.x;
    const int d0 = blockIdx.x * 4;
    const int c0 = blockIdx.y * 16;

    #pragma unroll
    for (int i = 0; i < 9; ++i) {
        int idx = t + i * 256;
        int cl = idx / 144;
        int nl = idx - cl * 144;
        Wf[cl][nl] = w[(size_t)(c0 + cl) * C3 + d0 * 36 + nl];
    }
    __syncthreads();
    #pragma unroll
    for (int i = 0; i < 9; ++i) {
        int idx = t + i * 256;
        int r  = idx >> 4;
        int cc = idx & 15;
        int dd = r / 36;
        int th = r - dd * 36;
        float val = Wf[cc][dd * 36 + th];
        u16 hb = f2bf(val);
        int np = th * 64 + d0 + dd;
        size_t o = (size_t)np * CDIM + sw32i(np, c0 + cc);
        wh[o] = hb;
        wl[o] = f2bf(val - bf2f(hb));
    }
}

// ---------------------------------------------------------------------------
// 0c: w_proj[k][n] -> wph/wpl [n][k] bf16 split, SW32-swizzled by row n.
//     (launched AFTER qkv_mfma: aliases the then-dead wh/wl region)
// ---------------------------------------------------------------------------
__launch_bounds__(256)
__global__ void split_wp(const float* __restrict__ w,
                         u16* __restrict__ wph, u16* __restrict__ wpl) {
    __shared__ float Tf[64][65];
    const int t  = threadIdx.x;
    const int n0 = blockIdx.x * 64;
    const int k0 = blockIdx.y * 64;

    #pragma unroll
    for (int i = 0; i < 4; ++i) {
        int kl = (t >> 4) + i * 16;
        int nl = (t & 15) * 4;
        float4 v4 = *(const float4*)&w[(size_t)(k0 + kl) * CDIM + n0 + nl];
        Tf[kl][nl + 0] = v4.x; Tf[kl][nl + 1] = v4.y;
        Tf[kl][nl + 2] = v4.z; Tf[kl][nl + 3] = v4.w;
    }
    __syncthreads();
    #pragma unroll
    for (int i = 0; i < 4; ++i) {
        int nr = (t >> 4) + i * 16;
        int k4 = (t & 15) * 4;
        u16 hs[4], ls[4];
        #pragma unroll
        for (int j = 0; j < 4; ++j) {
            float val = Tf[k4 + j][nr];
            hs[j] = f2bf(val);
            ls[j] = f2bf(val - bf2f(hs[j]));
        }
        int n = n0 + nr;
        int ksw = sw32i(n, k0 + k4);
        *(ushort4*)&wph[(size_t)n * CDIM + ksw] = make_ushort4(hs[0], hs[1], hs[2], hs[3]);
        *(ushort4*)&wpl[(size_t)n * CDIM + ksw] = make_ushort4(ls[0], ls[1], ls[2], ls[3]);
    }
}

// ---------------------------------------------------------------------------
// 1: QKV GEMM bf16x3 MFMA.  Outputs: Qp packed u32 (pre-scaled 8*log2e),
//    Kh/Kl planar SW64-swizzled [bh][p][d], Vh/Vl planar plain [bh][p][d].
// ---------------------------------------------------------------------------
__launch_bounds__(256)
__global__ void qkv_mfma(const u16* __restrict__ xh, const u16* __restrict__ xl,
                         const u16* __restrict__ wh, const u16* __restrict__ wl,
                         unsigned* __restrict__ Qp,
                         u16* __restrict__ Khg, u16* __restrict__ Klg,
                         u16* __restrict__ Vhg, u16* __restrict__ Vlg) {
    __shared__ u16 Ah[128][32];
    __shared__ u16 Al[128][32];
    __shared__ u16 Bh[128][32];
    __shared__ u16 Bl[128][32];

    const int tid = threadIdx.x;
    const int l   = tid & 63;
    const int w   = tid >> 6;
    const int lm  = l & 15;
    const int lg  = l >> 4;
    const int wr  = w >> 1;
    const int wc  = w & 1;
    const int m0  = blockIdx.x * 128;
    const int n0  = blockIdx.y * 128;
    const int b   = m0 >> 10;
    const int p0  = m0 & 1023;

    const size_t xbase = ((size_t)(b * NTOK) + p0) * CDIM;
    const int lrow = l >> 2;
    const int kq   = (l & 3) * 8;
    const int asw  = (lg ^ ((lm >> 1) & 3)) * 8;   // SW32 fragment offset

    f4v acc[4][4];
    #pragma unroll
    for (int i = 0; i < 4; ++i)
        #pragma unroll
        for (int j = 0; j < 4; ++j)
            acc[i][j] = (f4v){0.f, 0.f, 0.f, 0.f};

    for (int k0 = 0; k0 < CDIM; k0 += 32) {
        #pragma unroll
        for (int i = 0; i < 2; ++i) {
            int ch = w * 2 + i;
            int m  = ch * 16 + lrow;
            int lo = ch * 512;
            gload16(xh + xbase + (size_t)m * CDIM + k0 + kq, &Ah[0][0] + lo);
            gload16(xl + xbase + (size_t)m * CDIM + k0 + kq, &Al[0][0] + lo);
            gload16(wh + (size_t)(n0 + m) * CDIM + k0 + kq,  &Bh[0][0] + lo);
            gload16(wl + (size_t)(n0 + m) * CDIM + k0 + kq,  &Bl[0][0] + lo);
        }
        __syncthreads();

        s8v ah[4], al[4], bh[4], bl[4];
        #pragma unroll
        for (int mi = 0; mi < 4; ++mi) {
            int row = wr * 64 + mi * 16 + lm;
            ah[mi] = *(const s8v*)&Ah[row][asw];
            al[mi] = *(const s8v*)&Al[row][asw];
        }
        #pragma unroll
        for (int ni = 0; ni < 4; ++ni) {
            int row = wc * 64 + ni * 16 + lm;
            bh[ni] = *(const s8v*)&Bh[row][asw];
            bl[ni] = *(const s8v*)&Bl[row][asw];
        }
        __builtin_amdgcn_s_setprio(1);
        #pragma unroll
        for (int mi = 0; mi < 4; ++mi)
            #pragma unroll
            for (int ni = 0; ni < 4; ++ni) {
                acc[mi][ni] = MFMA16(ah[mi], bh[ni], acc[mi][ni]);
                acc[mi][ni] = MFMA16(ah[mi], bl[ni], acc[mi][ni]);
                acc[mi][ni] = MFMA16(al[mi], bh[ni], acc[mi][ni]);
            }
        __builtin_amdgcn_s_setprio(0);
        __syncthreads();
    }

    const int th = (n0 >> 6) + wc;
    const int t3 = th / 12;
    const int h  = th - t3 * 12;
    const size_t bhb = (size_t)(b * NHEAD + h) * NTOK;

    if (t3 == 0) {
        unsigned* dst = Qp + bhb * DHEAD;
        #pragma unroll
        for (int mi = 0; mi < 4; ++mi)
            #pragma unroll
            for (int r = 0; r < 4; ++r) {
                int p = p0 + wr * 64 + mi * 16 + lg * 4 + r;
                #pragma unroll
                for (int ni = 0; ni < 4; ++ni)
                    dst[(size_t)p * DHEAD + ni * 16 + lm] =
                        packsplit(acc[mi][ni][r] * (8.0f * LOG2E));
            }
    } else if (t3 == 1) {
        u16* dh = Khg + bhb * DHEAD;
        u16* dl = Klg + bhb * DHEAD;
        #pragma unroll
        for (int mi = 0; mi < 4; ++mi)
            #pragma unroll
            for (int r = 0; r < 4; ++r) {
                int p = p0 + wr * 64 + mi * 16 + lg * 4 + r;
                #pragma unroll
                for (int ni = 0; ni < 4; ++ni) {
                    int d = ni * 16 + lm;
                    int dsw = (((d >> 3) ^ (p & 7)) << 3) | (d & 7);   // SW64
                    float val = acc[mi][ni][r];
                    u16 hb = f2bf(val);
                    dh[(size_t)p * DHEAD + dsw] = hb;
                    dl[(size_t)p * DHEAD + dsw] = f2bf(val - bf2f(hb));
                }
            }
    } else {
        u16* dh = Vhg + bhb * DHEAD;
        u16* dl = Vlg + bhb * DHEAD;
        #pragma unroll
        for (int mi = 0; mi < 4; ++mi)
            #pragma unroll
            for (int r = 0; r < 4; ++r) {
                int p = p0 + wr * 64 + mi * 16 + lg * 4 + r;
                #pragma unroll
                for (int ni = 0; ni < 4; ++ni) {
                    int d = ni * 16 + lm;
                    float val = acc[mi][ni][r];
                    u16 hb = f2bf(val);
                    dh[(size_t)p * DHEAD + d] = hb;
                    dl[(size_t)p * DHEAD + d] = f2bf(val - bf2f(hb));
                }
            }
    }
}

// ---------------------------------------------------------------------------
// 1b: V planar [bh][p][d] -> Vt planar [bh][d][p], SW64-swizzled by d within
//     each 64-p window (pre-swizzled source for gload_lds, m173 pattern).
// ---------------------------------------------------------------------------
__launch_bounds__(256)
__global__ void vt_split(const u16* __restrict__ Vh, const u16* __restrict__ Vl,
                         u16* __restrict__ Vth, u16* __restrict__ Vtl) {
    __shared__ u16 Th[64][72];
    __shared__ u16 Tl[64][72];
    const int t  = threadIdx.x;
    const int pt = blockIdx.x;        // 16
    const int bh = blockIdx.y;        // 96

    #pragma unroll
    for (int i = 0; i < 4; ++i) {
        int idx = t + i * 256;
        int pr  = idx >> 4;
        int c4  = (idx & 15) * 4;
        size_t src = ((size_t)bh * NTOK + pt * 64 + pr) * DHEAD + c4;
        *(ushort4*)&Th[pr][c4] = *(const ushort4*)&Vh[src];
        *(ushort4*)&Tl[pr][c4] = *(const ushort4*)&Vl[src];
    }
    __syncthreads();
    #pragma unroll
    for (int i = 0; i < 4; ++i) {
        int idx   = t + i * 256;
        int plane = idx >> 9;
        int rem   = idx & 511;
        int d     = rem >> 3;
        int gp    = rem & 7;          // stored group position
        int gs    = gp ^ (d & 7);     // source p-group (SW64 pre-swizzle)
        u16 tmp[8];
        #pragma unroll
        for (int j = 0; j < 8; ++j)
            tmp[j] = plane ? Tl[gs * 8 + j][d] : Th[gs * 8 + j][d];
        u16* outp = plane ? Vtl : Vth;
        size_t dst = ((size_t)bh * DHEAD + d) * NTOK + pt * 64 + gp * 8;
        *(ushort4*)&outp[dst]     = make_ushort4(tmp[0], tmp[1], tmp[2], tmp[3]);
        *(ushort4*)&outp[dst + 4] = make_ushort4(tmp[4], tmp[5], tmp[6], tmp[7]);
    }
}

// ---------------------------------------------------------------------------
// 2: MFMA flash attention (LDS-staged, conflict-free swizzles, XCD-grouped
//    grid, exp2-domain softmax, NO setprio — it fences compiler scheduling).
// ---------------------------------------------------------------------------
__launch_bounds__(256)
__global__ void attn_mfma(const unsigned* __restrict__ Qp,
                          const u16* __restrict__ Khg, const u16* __restrict__ Klg,
                          const u16* __restrict__ Vth, const u16* __restrict__ Vtl,
                          u16* __restrict__ ctxh, u16* __restrict__ ctxl) {
    __shared__ u16 Kh[64][64];
    __shared__ u16 Kl[64][64];
    __shared__ u16 Vh[64][64];
    __shared__ u16 Vl[64][64];
    __shared__ u16 Ph[128][64];

    const int tid = threadIdx.x;
    const int l  = tid & 63;
    const int w  = tid >> 6;
    const int lm = l & 15;
    const int lg = l >> 4;

    // XCD-aware decode: bid&7 = xcd; each XCD gets 12 bh with all 8 q-blocks.
    const int bid = blockIdx.x;
    const int xcd = bid & 7;
    const int k_  = bid >> 3;               // 0..95
    const int bh  = xcd * 12 + (k_ >> 3);   // 0..95
    const int p0  = (k_ & 7) * 128;

    const unsigned* Qb = Qp + (size_t)bh * NTOK * DHEAD;
    const u16* Kb_h = Khg + (size_t)bh * NTOK * DHEAD;
    const u16* Kb_l = Klg + (size_t)bh * NTOK * DHEAD;
    const u16* Vb_h = Vth + (size_t)bh * DHEAD * NTOK;
    const u16* Vb_l = Vtl + (size_t)bh * DHEAD * NTOK;

    // Q fragments (packed, pre-scaled by 8*log2e)
    s8v qh[2][2], ql[2][2];
    #pragma unroll
    for (int t = 0; t < 2; ++t)
        #pragma unroll
        for (int kk = 0; kk < 2; ++kk) {
            const unsigned* src = Qb + (size_t)(p0 + w * 32 + t * 16 + lm) * DHEAD + kk * 32 + lg * 8;
            uint4 a0 = *(const uint4*)src;
            uint4 a1 = *(const uint4*)(src + 4);
            unpack8(a0, a1, qh[t][kk], ql[t][kk]);
        }

    f4v o[2][4];
    float mrun[2][4], lrun[2][4];
    #pragma unroll
    for (int t = 0; t < 2; ++t)
        #pragma unroll
        for (int c = 0; c < 4; ++c)
            o[t][c] = (f4v){0.f, 0.f, 0.f, 0.f};
    #pragma unroll
    for (int t = 0; t < 2; ++t)
        #pragma unroll
        for (int i = 0; i < 4; ++i) { mrun[t][i] = -3.0e38f; lrun[t][i] = 0.f; }

    const int fsw = (l & 7) * 8;      // 16B block within a 128B row for DMA
    const int r8  = l >> 3;           // row-in-chunk (8 rows of 128B per 1KB chunk)

    for (int kt = 0; kt < 16; ++kt) {
        __syncthreads();
        // stage K(h,l) and Vt(h,l): 8 chunks each, wave w does chunks w*2,w*2+1
        #pragma unroll
        for (int i = 0; i < 2; ++i) {
            int ch = w * 2 + i;
            int lo = ch * 512;
            size_t krow = (size_t)(kt * 64 + ch * 8 + r8) * DHEAD + fsw;
            gload16(Kb_h + krow, &Kh[0][0] + lo);
            gload16(Kb_l + krow, &Kl[0][0] + lo);
            size_t vrow = (size_t)(ch * 8 + r8) * NTOK + kt * 64 + fsw;
            gload16(Vb_h + vrow, &Vh[0][0] + lo);
            gload16(Vb_l + vrow, &Vl[0][0] + lo);
        }
        __syncthreads();

        // S = Q.K^T (bf16x3)
        f4v sa[2][4];
        #pragma unroll
        for (int t = 0; t < 2; ++t)
            #pragma unroll
            for (int c = 0; c < 4; ++c)
                sa[t][c] = (f4v){0.f, 0.f, 0.f, 0.f};

        #pragma unroll
        for (int kk = 0; kk < 2; ++kk)
            #pragma unroll
            for (int c = 0; c < 4; ++c) {
                int row = c * 16 + lm;
                int off = (((kk * 4 + lg) ^ (lm & 7))) * 8;   // SW64
                s8v kh = *(const s8v*)&Kh[row][off];
                s8v kl = *(const s8v*)&Kl[row][off];
                #pragma unroll
                for (int t = 0; t < 2; ++t) {
                    sa[t][c] = MFMA16(qh[t][kk], kh, sa[t][c]);
                    sa[t][c] = MFMA16(qh[t][kk], kl, sa[t][c]);
                    sa[t][c] = MFMA16(ql[t][kk], kh, sa[t][c]);
                }
            }

        // online softmax (exp2 domain); P bf16-hi to swizzled wave-private LDS
        #pragma unroll
        for (int t = 0; t < 2; ++t) {
            float f_[4];
            #pragma unroll
            for (int i = 0; i < 4; ++i) {
                float mt = fmaxf(fmaxf(sa[t][0][i], sa[t][1][i]),
                                 fmaxf(sa[t][2][i], sa[t][3][i]));
                #pragma unroll
                for (int off = 1; off < 16; off <<= 1)
                    mt = fmaxf(mt, __shfl_xor(mt, off, 16));
                float mn = fmaxf(mrun[t][i], mt);
                f_[i] = exp2f(mrun[t][i] - mn);
                mrun[t][i] = mn;
            }
            #pragma unroll
            for (int i = 0; i < 4; ++i) {
                int rp = w * 32 + t * 16 + lg * 4 + i;
                float rs = 0.f;
                #pragma unroll
                for (int c = 0; c < 4; ++c) {
                    float pv = exp2f(sa[t][c][i] - mrun[t][i]);
                    rs += pv;
                    int colg = c * 2 + (lm >> 3);
                    Ph[rp][((colg ^ (rp & 7)) << 3) + (lm & 7)] = f2bf(pv);
                }
                #pragma unroll
                for (int off = 1; off < 16; off <<= 1)
                    rs += __shfl_xor(rs, off, 16);
                lrun[t][i] = lrun[t][i] * f_[i] + rs;
                #pragma unroll
                for (int c = 0; c < 4; ++c)
                    o[t][c][i] *= f_[i];
            }
        }

        // O += P.V  (P rows are wave-private; compiler handles lgkmcnt)
        s8v pf[2][2];
        #pragma unroll
        for (int t = 0; t < 2; ++t)
            #pragma unroll
            for (int kk = 0; kk < 2; ++kk) {
                int row = w * 32 + t * 16 + lm;
                pf[t][kk] = *(const s8v*)&Ph[row][(((kk * 4 + lg) ^ (lm & 7))) * 8];
            }
        #pragma unroll
        for (int c = 0; c < 4; ++c)
            #pragma unroll
            for (int kk = 0; kk < 2; ++kk) {
                int row = c * 16 + lm;
                int off = (((kk * 4 + lg) ^ (lm & 7))) * 8;
                s8v vh = *(const s8v*)&Vh[row][off];
                s8v vl = *(const s8v*)&Vl[row][off];
                #pragma unroll
                for (int t = 0; t < 2; ++t) {
                    o[t][c] = MFMA16(pf[t][kk], vh, o[t][c]);
                    o[t][c] = MFMA16(pf[t][kk], vl, o[t][c]);
                }
            }
    }

    // epilogue: ctx split bf16, SW32-swizzled by row m
    const int b  = bh / NHEAD;
    const int hh = bh - b * NHEAD;
    #pragma unroll
    for (int t = 0; t < 2; ++t)
        #pragma unroll
        for (int i = 0; i < 4; ++i) {
            float inv = 1.f / lrun[t][i];
            int p = p0 + w * 32 + t * 16 + lg * 4 + i;
            size_t m = (size_t)(b * NTOK) + p;
            #pragma unroll
            for (int c = 0; c < 4; ++c) {
                int col = hh * DHEAD + c * 16 + lm;
                int csw = sw32i(p, col);
                float val = o[t][c][i] * inv;
                u16 hb = f2bf(val);
                ctxh[m * CDIM + csw] = hb;
                ctxl[m * CDIM + csw] = f2bf(val - bf2f(hb));
            }
        }
}

// ---------------------------------------------------------------------------
// 3: proj GEMM bf16x3 MFMA computing out[c'][m] = sum_k W[k][c'] ctx[m][k].
// ---------------------------------------------------------------------------
__launch_bounds__(256)
__global__ void proj_mfma(const u16* __restrict__ wph, const u16* __restrict__ wpl,
                          const u16* __restrict__ cth, const u16* __restrict__ ctl,
                          float* __restrict__ out) {
    __shared__ u16 Awh[64][32];
    __shared__ u16 Awl[64][32];
    __shared__ u16 Bch[128][32];
    __shared__ u16 Bcl[128][32];

    const int tid = threadIdx.x;
    const int l   = tid & 63;
    const int w   = tid >> 6;
    const int lm  = l & 15;
    const int lg  = l >> 4;
    const int wr  = w >> 1;
    const int wc  = w & 1;
    const int c0  = blockIdx.x * 64;
    const int m0  = blockIdx.y * 128;
    const int b   = m0 >> 10;
    const int pl0 = m0 & 1023;

    const int lrow = l >> 2;
    const int kq   = (l & 3) * 8;
    const int asw  = (lg ^ ((lm >> 1) & 3)) * 8;

    f4v acc[2][4];
    #pragma unroll
    for (int i = 0; i < 2; ++i)
        #pragma unroll
        for (int j = 0; j < 4; ++j)
            acc[i][j] = (f4v){0.f, 0.f, 0.f, 0.f};

    for (int k0 = 0; k0 < CDIM; k0 += 32) {
        {
            int row = w * 16 + lrow;
            gload16(wph + (size_t)(c0 + row) * CDIM + k0 + kq, &Awh[0][0] + w * 512);
            gload16(wpl + (size_t)(c0 + row) * CDIM + k0 + kq, &Awl[0][0] + w * 512);
        }
        #pragma unroll
        for (int i = 0; i < 2; ++i) {
            int ch = w * 2 + i;
            int row = ch * 16 + lrow;
            gload16(cth + (size_t)(m0 + row) * CDIM + k0 + kq, &Bch[0][0] + ch * 512);
            gload16(ctl + (size_t)(m0 + row) * CDIM + k0 + kq, &Bcl[0][0] + ch * 512);
        }
        __syncthreads();

        s8v ah[2], al[2], bh[4], bl[4];
        #pragma unroll
        for (int mi = 0; mi < 2; ++mi) {
            int row = wr * 32 + mi * 16 + lm;
            ah[mi] = *(const s8v*)&Awh[row][asw];
            al[mi] = *(const s8v*)&Awl[row][asw];
        }
        #pragma unroll
        for (int ni = 0; ni < 4; ++ni) {
            int row = wc * 64 + ni * 16 + lm;
            bh[ni] = *(const s8v*)&Bch[row][asw];
            bl[ni] = *(const s8v*)&Bcl[row][asw];
        }
        __builtin_amdgcn_s_setprio(1);
        #pragma unroll
        for (int mi = 0; mi < 2; ++mi)
            #pragma unroll
            for (int ni = 0; ni < 4; ++ni) {
                acc[mi][ni] = MFMA16(ah[mi], bh[ni], acc[mi][ni]);
                acc[mi][ni] = MFMA16(ah[mi], bl[ni], acc[mi][ni]);
                acc[mi][ni] = MFMA16(al[mi], bh[ni], acc[mi][ni]);
            }
        __builtin_amdgcn_s_setprio(0);
        __syncthreads();
    }

    #pragma unroll
    for (int mi = 0; mi < 2; ++mi)
        #pragma unroll
        for (int r = 0; r < 4; ++r) {
            int cpr = c0 + wr * 32 + mi * 16 + lg * 4 + r;
            #pragma unroll
            for (int ni = 0; ni < 4; ++ni) {
                int p = pl0 + wc * 64 + ni * 16 + lm;
                out[((size_t)b * CDIM + cpr) * NTOK + p] = acc[mi][ni][r];
            }
        }
}

// ---------------------------------------------------------------------------
extern "C" void kernel_launch(void* const* d_in, const int* in_sizes, int n_in,
                              void* d_out, int out_size, void* d_ws, size_t ws_size,
                              hipStream_t stream) {
    (void)in_sizes; (void)n_in; (void)out_size; (void)ws_size;
    const float* x      = (const float*)d_in[0];
    const float* w_qkv  = (const float*)d_in[1];
    const float* w_proj = (const float*)d_in[2];
    float* out = (float*)d_out;

    const size_t NE = (size_t)NB * NHEAD * NTOK * DHEAD;   // 6,291,456
    char* w8 = (char*)d_ws;
    unsigned* Qp = (unsigned*)w8;                  // [0, 4NE)
    u16* Khg = (u16*)(w8 + 4 * NE);                // [4NE, 6NE)
    u16* Klg = Khg + NE;                           // [6NE, 8NE)
    u16* Vhg = (u16*)(w8 + 8 * NE);                // [8NE, 10NE)   (later ctxh)
    u16* Vlg = Vhg + NE;                           // [10NE, 12NE)  (later ctxl)
    u16* xh  = (u16*)(w8 + 12 * NE);               // [12NE, 14NE)  (later Vth)
    u16* xl  = xh + NE;                            // [14NE, 16NE)  (later Vtl)
    u16* wh  = (u16*)(w8 + 16 * NE);               // C3*CDIM u16
    u16* wl  = wh + (size_t)C3 * CDIM;
    // aliases (lifetimes disjoint; peak footprint 16NE + 7.08MB = 107.75 MB):
    u16* Vth  = xh;   u16* Vtl  = xl;
    u16* ctxh = Vhg;  u16* ctxl = Vlg;
    u16* wph  = wh;   u16* wpl  = wh + (size_t)CDIM * CDIM;

    split_x <<<dim3(16, 12, 8), 256, 0, stream>>>(x, xh, xl);
    split_w <<<dim3(16, 48),    256, 0, stream>>>(w_qkv, wh, wl);
    qkv_mfma<<<dim3(64, 18),    256, 0, stream>>>(xh, xl, wh, wl, Qp, Khg, Klg, Vhg, Vlg);
    split_wp<<<dim3(12, 12),    256, 0, stream>>>(w_proj, wph, wpl);
    vt_split<<<dim3(16, 96),    256, 0, stream>>>(Vhg, Vlg, Vth, Vtl);
    attn_mfma<<<dim3(768),      256, 0, stream>>>(Qp, Khg, Klg, Vth, Vtl, ctxh, ctxl);
    proj_mfma<<<dim3(12, 64),   256, 0, stream>>>(wph, wpl, ctxh, ctxl, out);
}